// Round 1
// baseline (14482.774 us; speedup 1.0000x reference)
//
#include <hip/hip_runtime.h>
#include <math.h>

// Model constants
#define TT      4608   // B*N
#define BB      8
#define NTOK    576    // 24*24
#define CDIM    256
#define NHEADS  8
#define HDIM    32
#define HIDDIM  1024

__device__ __forceinline__ float gelu_f(float x) {
    return 0.5f * x * (1.0f + erff(x * 0.70710678118654752f));
}

__device__ __forceinline__ void bases6(float v, float* out) {
    const float grid0 = -1.0f, step = 0.4f;
    float e[6]; float s = 0.f;
#pragma unroll
    for (int g = 0; g < 6; g++) {
        float d = v - (grid0 + step * g);
        e[g] = __expf(-d * d * 12.5f);
        s += e[g];
    }
    float inv = 1.f / (s + 1e-8f);
#pragma unroll
    for (int g = 0; g < 6; g++) out[g] = e[g] * inv;
}

// ---------------- transpose (B,C,H,W) -> (T=B*N, C) ----------------
__global__ __launch_bounds__(256) void k_transpose(const float* __restrict__ in,
                                                   float* __restrict__ out) {
    int idx = blockIdx.x * 256 + threadIdx.x;  // over TT*CDIM
    if (idx >= TT * CDIM) return;
    int t = idx >> 8, c = idx & 255;
    int b = t / NTOK, n = t % NTOK;
    out[idx] = in[(b * CDIM + c) * NTOK + n];
}

// ---------------- expand normalized RBF bases: x (flat) -> bases (flat*6) ----------------
__global__ __launch_bounds__(256) void k_expand(const float* __restrict__ x,
                                                float* __restrict__ bases, int total) {
    int idx = blockIdx.x * 256 + threadIdx.x;
    if (idx >= total) return;
    float b6[6];
    bases6(x[idx], b6);
#pragma unroll
    for (int g = 0; g < 6; g++) bases[idx * 6 + g] = b6[g];
}

// ---------------- two-segment GEMM: C[M,NN] = act( A1@W1^T + A2@W2^T ) ----------------
// A1 (M,K1), A2 (M,K2), W1 (NN,K1), W2 (NN,K2); all row-major, K contiguous.
// Tiles: 64x64, BK=16, 256 threads, 4x4 per thread. K1 % 16 == 0 required.
__global__ __launch_bounds__(256) void gemm2seg(const float* __restrict__ A1, int K1,
                                                const float* __restrict__ A2, int K2,
                                                const float* __restrict__ W1,
                                                const float* __restrict__ W2,
                                                float* __restrict__ Cout, int NN, int act) {
    __shared__ float As[16][64];
    __shared__ float Wsh[16][64];
    const int bn = blockIdx.x * 64;
    const int bm = blockIdx.y * 64;
    const int tid = threadIdx.x;
    const int tx = tid & 15, ty = tid >> 4;
    float acc[4][4] = {};
    const int Ktot = K1 + K2;
    const int lrow = tid >> 2;          // 0..63 (row of tile being loaded)
    const int lk4  = (tid & 3) * 4;     // 0,4,8,12

    for (int kt = 0; kt < Ktot; kt += 16) {
        const float* Aseg; const float* Wseg; int ld, kofs;
        if (kt < K1) { Aseg = A1; Wseg = W1; ld = K1; kofs = kt; }
        else         { Aseg = A2; Wseg = W2; ld = K2; kofs = kt - K1; }
        float4 av = *(const float4*)(Aseg + (size_t)(bm + lrow) * ld + kofs + lk4);
        float4 wv = *(const float4*)(Wseg + (size_t)(bn + lrow) * ld + kofs + lk4);
        As[lk4 + 0][lrow] = av.x; As[lk4 + 1][lrow] = av.y;
        As[lk4 + 2][lrow] = av.z; As[lk4 + 3][lrow] = av.w;
        Wsh[lk4 + 0][lrow] = wv.x; Wsh[lk4 + 1][lrow] = wv.y;
        Wsh[lk4 + 2][lrow] = wv.z; Wsh[lk4 + 3][lrow] = wv.w;
        __syncthreads();
#pragma unroll
        for (int k = 0; k < 16; k++) {
            float4 a4 = *(const float4*)&As[k][ty * 4];
            float4 w4 = *(const float4*)&Wsh[k][tx * 4];
            float a_[4] = {a4.x, a4.y, a4.z, a4.w};
            float w_[4] = {w4.x, w4.y, w4.z, w4.w};
#pragma unroll
            for (int i = 0; i < 4; i++)
#pragma unroll
                for (int j = 0; j < 4; j++) acc[i][j] += a_[i] * w_[j];
        }
        __syncthreads();
    }
#pragma unroll
    for (int i = 0; i < 4; i++) {
        float4 o4;
        float* oo = (float*)&o4;
#pragma unroll
        for (int j = 0; j < 4; j++) {
            float v = acc[i][j];
            if (act == 1) v = gelu_f(v);
            oo[j] = v;
        }
        *(float4*)&Cout[(size_t)(bm + ty * 4 + i) * NN + bn + tx * 4] = o4;
    }
}

// ---------------- relative-position bias: (NH, N, N) ----------------
__global__ __launch_bounds__(256) void k_bias(const float* __restrict__ rb,  // (8,2)
                                              const float* __restrict__ rs,  // (8,2,6)
                                              float* __restrict__ Bias) {    // (8,576,576)
    int idx = blockIdx.x * 256 + threadIdx.x;
    if (idx >= NTOK * NTOK) return;
    int n = idx / NTOK, m = idx % NTOK;
    float r[2];
    r[0] = (float)((n / 24) - (m / 24)) * (1.0f / 23.0f);
    r[1] = (float)((n % 24) - (m % 24)) * (1.0f / 23.0f);
    float v[2][6];
    bases6(r[0], v[0]);
    bases6(r[1], v[1]);
#pragma unroll
    for (int h = 0; h < NHEADS; h++) {
        float s = 0.f;
#pragma unroll
        for (int i = 0; i < 2; i++) {
            s += rb[h * 2 + i] * r[i];
#pragma unroll
            for (int g = 0; g < 6; g++) s += rs[(h * 2 + i) * 6 + g] * v[i][g];
        }
        Bias[(size_t)h * NTOK * NTOK + idx] = s;
    }
}

// ---------------- fused attention: softmax(QK^T*scale + bias) @ V ----------------
// block: 256 threads, handles (b, h, 16 q-rows). QKV layout (T, 768): q|k|v each col h*32+d.
__global__ __launch_bounds__(256) void k_attn(const float* __restrict__ QKV,
                                              const float* __restrict__ Bias,
                                              float* __restrict__ O, float scale) {
    const int b = blockIdx.z, h = blockIdx.y, n0 = blockIdx.x * 16;
    __shared__ float qs[16][32];
    __shared__ float sc[16][576];
    __shared__ float st[64][32];
    const int tid = threadIdx.x;
    for (int idx = tid; idx < 16 * 32; idx += 256) {
        int r = idx >> 5, d = idx & 31;
        qs[r][d] = QKV[(size_t)(b * NTOK + n0 + r) * 768 + h * 32 + d];
    }
    __syncthreads();
    // score phase
    for (int mc = 0; mc < NTOK; mc += 64) {
        for (int idx = tid; idx < 64 * 32; idx += 256) {
            int j = idx >> 5, d = idx & 31;
            st[j][d] = QKV[(size_t)(b * NTOK + mc + j) * 768 + 256 + h * 32 + d];
        }
        __syncthreads();
        for (int idx = tid; idx < 16 * 64; idx += 256) {
            int r = idx >> 6, c2 = idx & 63;
            float s = 0.f;
#pragma unroll
            for (int d = 0; d < 32; d++) s += qs[r][d] * st[c2][d];
            s = s * scale + Bias[((size_t)h * NTOK + (n0 + r)) * NTOK + mc + c2];
            sc[r][mc + c2] = s;
        }
        __syncthreads();
    }
    // softmax per row (4 waves x 4 rows)
    const int wave = tid >> 6, lane = tid & 63;
    for (int r = wave; r < 16; r += 4) {
        float mx = -1e30f;
        for (int m = lane; m < NTOK; m += 64) mx = fmaxf(mx, sc[r][m]);
#pragma unroll
        for (int off = 32; off; off >>= 1) mx = fmaxf(mx, __shfl_xor(mx, off));
        float sum = 0.f;
        for (int m = lane; m < NTOK; m += 64) {
            float p = __expf(sc[r][m] - mx);
            sc[r][m] = p; sum += p;
        }
#pragma unroll
        for (int off = 32; off; off >>= 1) sum += __shfl_xor(sum, off);
        float inv = 1.f / sum;
        for (int m = lane; m < NTOK; m += 64) sc[r][m] *= inv;
    }
    __syncthreads();
    // AV phase
    float acc0 = 0.f, acc1 = 0.f;
    const int rr = tid >> 5, d = tid & 31;   // rr 0..7
    for (int mc = 0; mc < NTOK; mc += 64) {
        for (int idx = tid; idx < 64 * 32; idx += 256) {
            int j = idx >> 5, dd = idx & 31;
            st[j][dd] = QKV[(size_t)(b * NTOK + mc + j) * 768 + 512 + h * 32 + dd];
        }
        __syncthreads();
#pragma unroll 8
        for (int j = 0; j < 64; j++) {
            acc0 += sc[rr][mc + j] * st[j][d];
            acc1 += sc[rr + 8][mc + j] * st[j][d];
        }
        __syncthreads();
    }
    O[(size_t)(b * NTOK + n0 + rr) * CDIM + h * 32 + d] = acc0;
    O[(size_t)(b * NTOK + n0 + rr + 8) * CDIM + h * 32 + d] = acc1;
}

// ---------------- layernorm (+residual add) over C=256 ----------------
__global__ __launch_bounds__(256) void k_ln_add(const float* __restrict__ Xin,
                                                const float* __restrict__ SE,
                                                const float* __restrict__ g,
                                                const float* __restrict__ bb,
                                                float* __restrict__ Out) {
    int t = blockIdx.x, c = threadIdx.x;
    float v = Xin[t * 256 + c];
    float s1 = v, s2 = v * v;
#pragma unroll
    for (int off = 32; off; off >>= 1) { s1 += __shfl_xor(s1, off); s2 += __shfl_xor(s2, off); }
    __shared__ float p1[4], p2[4];
    int wv_ = c >> 6, ln = c & 63;
    if (ln == 0) { p1[wv_] = s1; p2[wv_] = s2; }
    __syncthreads();
    s1 = p1[0] + p1[1] + p1[2] + p1[3];
    s2 = p2[0] + p2[1] + p2[2] + p2[3];
    float m = s1 * (1.f / 256.f);
    float var = s2 * (1.f / 256.f) - m * m;
    float y = (v - m) * rsqrtf(var + 1e-5f) * g[c] + bb[c];
    Out[t * 256 + c] = SE[t * 256 + c] + y;
}

__global__ __launch_bounds__(256) void k_ln_gelu(const float* __restrict__ Xin,
                                                 const float* __restrict__ g,
                                                 const float* __restrict__ bb,
                                                 float* __restrict__ Out) {
    int t = blockIdx.x, c = threadIdx.x;
    float v = Xin[t * 256 + c];
    float s1 = v, s2 = v * v;
#pragma unroll
    for (int off = 32; off; off >>= 1) { s1 += __shfl_xor(s1, off); s2 += __shfl_xor(s2, off); }
    __shared__ float p1[4], p2[4];
    int wv_ = c >> 6, ln = c & 63;
    if (ln == 0) { p1[wv_] = s1; p2[wv_] = s2; }
    __syncthreads();
    s1 = p1[0] + p1[1] + p1[2] + p1[3];
    s2 = p2[0] + p2[1] + p2[2] + p2[3];
    float m = s1 * (1.f / 256.f);
    float var = s2 * (1.f / 256.f) - m * m;
    float y = (v - m) * rsqrtf(var + 1e-5f) * g[c] + bb[c];
    Out[t * 256 + c] = gelu_f(y);
}

// ---------------- mean pool over N tokens ----------------
__global__ __launch_bounds__(256) void k_meanpool(const float* __restrict__ X,
                                                  float* __restrict__ si, int colofs) {
    int idx = blockIdx.x * 256 + threadIdx.x;  // 8*256
    if (idx >= BB * CDIM) return;
    int b = idx >> 8, c = idx & 255;
    float s = 0.f;
    for (int n = 0; n < NTOK; n++) s += X[(size_t)(b * NTOK + n) * CDIM + c];
    si[b * 512 + colofs + c] = s * (1.f / 576.f);
}

// ---------------- small KAN (head): out[t,o] = act( A1[t]@W1[o] + A2[t]@W2[o] ) ----------------
__global__ __launch_bounds__(64) void k_small_kan(const float* __restrict__ A1, int K1,
                                                  const float* __restrict__ A2, int K2,
                                                  const float* __restrict__ W1,
                                                  const float* __restrict__ W2,
                                                  float* __restrict__ out, int NN, int act) {
    int o = blockIdx.x, t = blockIdx.y, ln = threadIdx.x;
    float s = 0.f;
    for (int k = ln; k < K1; k += 64) s += A1[t * K1 + k] * W1[o * K1 + k];
    for (int k = ln; k < K2; k += 64) s += A2[t * K2 + k] * W2[o * K2 + k];
#pragma unroll
    for (int off = 32; off; off >>= 1) s += __shfl_xor(s, off);
    if (ln == 0) {
        if (act == 1) s = gelu_f(s);
        else if (act == 2) s = 1.f / (1.f + __expf(-s));
        out[t * NN + o] = s;
    }
}

// ---------------- fi = [sg*w, ug*(1-w)] ----------------
__global__ void k_fi(const float* __restrict__ si, const float* __restrict__ wv,
                     float* __restrict__ fi) {
    int idx = blockIdx.x * 256 + threadIdx.x;
    if (idx >= BB * 512) return;
    int b = idx >> 9, i = idx & 511;
    float w = wv[b];
    fi[idx] = si[idx] * (i < 256 ? w : 1.f - w);
}

extern "C" void kernel_launch(void* const* d_in, const int* in_sizes, int n_in,
                              void* d_out, int out_size, void* d_ws, size_t ws_size,
                              hipStream_t stream) {
    (void)in_sizes; (void)n_in; (void)out_size; (void)ws_size;
    const float* sat_f = (const float*)d_in[0];
    const float* uav_f = (const float*)d_in[1];
    const float* s_qb  = (const float*)d_in[2];
    const float* s_qs  = (const float*)d_in[3];
    const float* s_rb  = (const float*)d_in[4];
    const float* s_rs  = (const float*)d_in[5];
    const float* u_qb  = (const float*)d_in[6];
    const float* u_qs  = (const float*)d_in[7];
    const float* u_rb  = (const float*)d_in[8];
    const float* u_rs  = (const float*)d_in[9];
    const float* r_w1b = (const float*)d_in[10];
    const float* r_w1s = (const float*)d_in[11];
    const float* r_w2b = (const float*)d_in[12];
    const float* r_w2s = (const float*)d_in[13];
    const float* r_lng = (const float*)d_in[14];
    const float* r_lnb = (const float*)d_in[15];
    const float* m_w1b = (const float*)d_in[16];
    const float* m_w1s = (const float*)d_in[17];
    const float* m_w2b = (const float*)d_in[18];
    const float* m_w2s = (const float*)d_in[19];
    const float* m_w3b = (const float*)d_in[20];
    const float* m_w3s = (const float*)d_in[21];
    const float* f_wb  = (const float*)d_in[22];
    const float* f_ws  = (const float*)d_in[23];
    const float* f_lng = (const float*)d_in[24];
    const float* f_lnb = (const float*)d_in[25];

    float* ws = (float*)d_ws;
    float* xs   = ws; ws += TT * CDIM;            // current sat (T,256)
    float* xu   = ws; ws += TT * CDIM;            // current uav
    float* QKV  = ws; ws += TT * 768;             // (T,768)
    float* EB   = ws; ws += 7077888;              // bases buffer (max T*1536 == 1152*6144)
    float* OB   = ws; ws += TT * CDIM;            // attention output
    float* SEb  = ws; ws += TT * CDIM;            // se
    float* H1   = ws; ws += TT * HIDDIM;          // refine hidden (aliases BIAS)
    float* BIAS = H1;                             // (8,576,576) = 2.65M < T*1024
    float* H2   = ws; ws += TT * CDIM;
    float* si   = ws; ws += BB * 512;
    float* SB   = ws; ws += BB * HIDDIM * 6;      // small bases (max 8*1024*6)
    float* h1f  = ws; ws += BB * HIDDIM;
    float* h2f  = ws; ws += BB * 64;
    float* wv   = ws; ws += BB;
    float* fi   = ws; ws += BB * 512;
    float* ftmp = ws; ws += BB * CDIM;

    const float scale = 0.17677669529663687f;  // 32^-0.5

    k_transpose<<<TT, 256, 0, stream>>>(sat_f, xs);
    k_transpose<<<TT, 256, 0, stream>>>(uav_f, xu);

    for (int l = 0; l < 3; l++) {
        for (int st2 = 0; st2 < 2; st2++) {
            float* X = st2 ? xu : xs;
            const float* qb = (st2 ? u_qb : s_qb) + l * 4 * 256 * 256;
            const float* qs = (st2 ? u_qs : s_qs) + l * 4 * 256 * 256 * 6;
            const float* rb = (st2 ? u_rb : s_rb) + l * 16;
            const float* rs = (st2 ? u_rs : s_rs) + l * 96;

            // QKV
            k_expand<<<(TT * 256 + 255) / 256, 256, 0, stream>>>(X, EB, TT * 256);
            gemm2seg<<<dim3(768 / 64, TT / 64), 256, 0, stream>>>(
                X, 256, EB, 1536, qb, qs, QKV, 768, 0);
            // bias + attention
            k_bias<<<(NTOK * NTOK + 255) / 256, 256, 0, stream>>>(rb, rs, BIAS);
            k_attn<<<dim3(NTOK / 16, NHEADS, BB), 256, 0, stream>>>(QKV, BIAS, OB, scale);
            // proj
            k_expand<<<(TT * 256 + 255) / 256, 256, 0, stream>>>(OB, EB, TT * 256);
            gemm2seg<<<dim3(256 / 64, TT / 64), 256, 0, stream>>>(
                OB, 256, EB, 1536, qb + 3 * 256 * 256, qs + 3 * 256 * 256 * 6, SEb, 256, 0);
            // refine w1 (+gelu)
            k_expand<<<(TT * 256 + 255) / 256, 256, 0, stream>>>(SEb, EB, TT * 256);
            gemm2seg<<<dim3(1024 / 64, TT / 64), 256, 0, stream>>>(
                SEb, 256, EB, 1536, r_w1b + l * 1024 * 256, r_w1s + l * 1024 * 256 * 6,
                H1, 1024, 1);
            // refine w2 chunked (4 x 1152 rows)
            for (int ch = 0; ch < 4; ch++) {
                float* h1c = H1 + (size_t)ch * 1152 * 1024;
                k_expand<<<(1152 * 1024 + 255) / 256, 256, 0, stream>>>(h1c, EB, 1152 * 1024);
                gemm2seg<<<dim3(256 / 64, 1152 / 64), 256, 0, stream>>>(
                    h1c, 1024, EB, 6144, r_w2b + l * 256 * 1024, r_w2s + l * 256 * 1024 * 6,
                    H2 + (size_t)ch * 1152 * 256, 256, 0);
            }
            // LN + residual -> new X
            k_ln_add<<<TT, 256, 0, stream>>>(H2, SEb, r_lng + l * 256, r_lnb + l * 256, X);
        }
    }

    // final head
    k_meanpool<<<8, 256, 0, stream>>>(xs, si, 0);
    k_meanpool<<<8, 256, 0, stream>>>(xu, si, 256);
    k_expand<<<(BB * 512 + 255) / 256, 256, 0, stream>>>(si, SB, BB * 512);
    k_small_kan<<<dim3(1024, BB), 64, 0, stream>>>(si, 512, SB, 3072, m_w1b, m_w1s, h1f, 1024, 1);
    k_expand<<<(BB * 1024 + 255) / 256, 256, 0, stream>>>(h1f, SB, BB * 1024);
    k_small_kan<<<dim3(64, BB), 64, 0, stream>>>(h1f, 1024, SB, 6144, m_w2b, m_w2s, h2f, 64, 1);
    k_expand<<<(BB * 64 + 255) / 256, 256, 0, stream>>>(h2f, SB, BB * 64);
    k_small_kan<<<dim3(1, BB), 64, 0, stream>>>(h2f, 64, SB, 384, m_w3b, m_w3s, wv, 1, 2);
    k_fi<<<16, 256, 0, stream>>>(si, wv, fi);
    k_expand<<<(BB * 512 + 255) / 256, 256, 0, stream>>>(fi, SB, BB * 512);
    k_small_kan<<<dim3(256, BB), 64, 0, stream>>>(fi, 512, SB, 3072, f_wb, f_ws, ftmp, 256, 0);
    k_ln_gelu<<<8, 256, 0, stream>>>(ftmp, f_lng, f_lnb, (float*)d_out);
}

// Round 2
// 2177.776 us; speedup vs baseline: 6.6503x; 6.6503x over previous
//
#include <hip/hip_runtime.h>
#include <math.h>

#define TT      4608   // B*N
#define BB      8
#define NTOK    576
#define CDIM    256
#define NHEADS  8
#define HIDDIM  1024

typedef unsigned short ushort_t;
typedef __attribute__((ext_vector_type(8))) short bf8s;   // 8 bf16 (4 VGPRs)
typedef __attribute__((ext_vector_type(4))) float f4;

__device__ __forceinline__ f4 mfma16(bf8s a, bf8s b, f4 c) {
    return __builtin_amdgcn_mfma_f32_16x16x32_bf16(a, b, c, 0, 0, 0);
}

__device__ __forceinline__ unsigned short f2bf(float x) {
    union { float f; unsigned int u; } v; v.f = x;
    unsigned int r = v.u + 0x7FFFu + ((v.u >> 16) & 1u);
    return (unsigned short)(r >> 16);
}
__device__ __forceinline__ float bf2f(unsigned short h) {
    union { unsigned int u; float f; } v; v.u = ((unsigned int)h) << 16;
    return v.f;
}

__device__ __forceinline__ float gelu_f(float x) {
    return 0.5f * x * (1.0f + erff(x * 0.70710678118654752f));
}

__device__ __forceinline__ void bases6(float v, float* out) {
    float e[6]; float s = 0.f;
#pragma unroll
    for (int g = 0; g < 6; g++) {
        float d = v - (-1.0f + 0.4f * g);
        e[g] = __expf(-d * d * 12.5f);
        s += e[g];
    }
    float inv = 1.f / (s + 1e-8f);
#pragma unroll
    for (int g = 0; g < 6; g++) out[g] = e[g] * inv;
}

__device__ __forceinline__ void gload16(const void* g, void* l) {
    __builtin_amdgcn_global_load_lds(
        (const __attribute__((address_space(1))) unsigned int*)g,
        (__attribute__((address_space(3))) unsigned int*)l, 16, 0, 0);
}

// ---------------- transpose (B,C,H,W) -> (T, C) fp32 ----------------
__global__ __launch_bounds__(256) void k_transpose(const float* __restrict__ in,
                                                   float* __restrict__ out) {
    int idx = blockIdx.x * 256 + threadIdx.x;
    if (idx >= TT * CDIM) return;
    int t = idx >> 8, c = idx & 255;
    int b = t / NTOK, n = t % NTOK;
    out[idx] = in[(b * CDIM + c) * NTOK + n];
}

// ---------------- expand: fp32 x (T,K1) -> bf16 [x | bases] (T, 7*K1) ----------------
__global__ __launch_bounds__(256) void k_expand7(const float* __restrict__ x,
                                                 unsigned short* __restrict__ out,
                                                 int K1, int total) {
    int idx = blockIdx.x * 256 + threadIdx.x;
    if (idx >= total) return;
    int t = idx / K1, i = idx - t * K1;
    float v = x[idx];
    size_t ro = (size_t)t * 7 * K1;
    out[ro + i] = f2bf(v);
    float b6[6]; bases6(v, b6);
    size_t o = ro + K1 + (size_t)i * 6;
#pragma unroll
    for (int g = 0; g < 6; g++) out[o + g] = f2bf(b6[g]);
}

// ---------------- expand half of H1 (bf16, T x 1024) -> bases bf16 (T, 3072) ----------------
__global__ __launch_bounds__(256) void k_ex_half(const unsigned short* __restrict__ h1,
                                                 unsigned short* __restrict__ out, int c0) {
    int idx = blockIdx.x * 256 + threadIdx.x;
    if (idx >= TT * 512) return;
    int t = idx >> 9, i = idx & 511;
    float v = bf2f(h1[t * 1024 + c0 + i]);
    float b6[6]; bases6(v, b6);
    size_t o = (size_t)t * 3072 + (size_t)i * 6;
#pragma unroll
    for (int g = 0; g < 6; g++) out[o + g] = f2bf(b6[g]);
}

// ---------------- weight repack: [base | spline] fp32 -> bf16 (R, 7*K1) ----------------
__global__ __launch_bounds__(256) void k_pack_cat(const float* __restrict__ base,
                                                  const float* __restrict__ spl,
                                                  unsigned short* __restrict__ out,
                                                  int R, int K1) {
    int K7 = 7 * K1;
    int idx = blockIdx.x * 256 + threadIdx.x;
    if (idx >= R * K7) return;
    int r = idx / K7, c = idx - r * K7;
    float v = (c < K1) ? base[(size_t)r * K1 + c] : spl[(size_t)r * 6 * K1 + (c - K1)];
    out[idx] = f2bf(v);
}

__global__ __launch_bounds__(256) void k_pack_str(const float* __restrict__ src,
                                                  unsigned short* __restrict__ out,
                                                  int R, int cols, int sstride, int sofs) {
    int idx = blockIdx.x * 256 + threadIdx.x;
    if (idx >= R * cols) return;
    int r = idx / cols, c = idx - r * cols;
    out[idx] = f2bf(src[(size_t)r * sstride + sofs + c]);
}

// ---------------- bf16 MFMA GEMM: C = act(A @ W^T) ----------------
// A (M,K) bf16 rm, W (NN,K) bf16 rm. BM x BN tile, BK=32, 4 waves (2x2).
// CMODE: 0 = store f32, 1 = += f32, 2 = store bf16
template<int BM, int BN, int ACT, int CMODE>
__global__ __launch_bounds__(256) void mgemm(const unsigned short* __restrict__ A,
                                             const unsigned short* __restrict__ W,
                                             void* __restrict__ Cv, int NN, int K) {
    constexpr int MF = BM / 32;
    constexpr int NF = BN / 32;
    __shared__ unsigned short As[BM * 32];
    __shared__ unsigned short Bs[BN * 32];
    const int tid = threadIdx.x, l = tid & 63, w = tid >> 6;
    const int wr = w >> 1, wc = w & 1;
    const int bm = blockIdx.y * BM, bn = blockIdx.x * BN;
    const int rowA = l >> 2;          // 0..15 within 16-row chunk
    const int colb = (l & 3) * 8;     // bf16 elem 0,8,16,24
    f4 acc[MF][NF];
#pragma unroll
    for (int m = 0; m < MF; m++)
#pragma unroll
        for (int n = 0; n < NF; n++) acc[m][n] = (f4){0.f, 0.f, 0.f, 0.f};

    for (int kt = 0; kt < K; kt += 32) {
#pragma unroll
        for (int it = 0; it < BM / 64; it++) {
            int c = it * 4 + w;
            int r = c * 16 + rowA;
            gload16(A + (size_t)(bm + r) * K + kt + colb, (void*)(As + r * 32 + colb));
        }
#pragma unroll
        for (int it = 0; it < BN / 64; it++) {
            int c = it * 4 + w;
            int r = c * 16 + rowA;
            gload16(W + (size_t)(bn + r) * K + kt + colb, (void*)(Bs + r * 32 + colb));
        }
        __syncthreads();
        bf8s af[MF], bfr[NF];
#pragma unroll
        for (int m = 0; m < MF; m++)
            af[m] = *(const bf8s*)&As[(wr * (BM / 2) + m * 16 + (l & 15)) * 32 + (l >> 4) * 8];
#pragma unroll
        for (int n = 0; n < NF; n++)
            bfr[n] = *(const bf8s*)&Bs[(wc * (BN / 2) + n * 16 + (l & 15)) * 32 + (l >> 4) * 8];
#pragma unroll
        for (int m = 0; m < MF; m++)
#pragma unroll
            for (int n = 0; n < NF; n++)
                acc[m][n] = mfma16(af[m], bfr[n], acc[m][n]);
        __syncthreads();
    }
#pragma unroll
    for (int m = 0; m < MF; m++)
#pragma unroll
        for (int n = 0; n < NF; n++)
#pragma unroll
            for (int j = 0; j < 4; j++) {
                int row = bm + wr * (BM / 2) + m * 16 + (l >> 4) * 4 + j;
                int col = bn + wc * (BN / 2) + n * 16 + (l & 15);
                float v = acc[m][n][j];
                if (ACT == 1) v = gelu_f(v);
                size_t o = (size_t)row * NN + col;
                if (CMODE == 0)      ((float*)Cv)[o] = v;
                else if (CMODE == 1) ((float*)Cv)[o] += v;
                else                 ((unsigned short*)Cv)[o] = f2bf(v);
            }
}

// ---------------- relative-position bias (NH,N,N) fp32 ----------------
__global__ __launch_bounds__(256) void k_bias(const float* __restrict__ rb,
                                              const float* __restrict__ rs,
                                              float* __restrict__ Bias) {
    int idx = blockIdx.x * 256 + threadIdx.x;
    if (idx >= NTOK * NTOK) return;
    int n = idx / NTOK, m = idx % NTOK;
    float r[2];
    r[0] = (float)((n / 24) - (m / 24)) * (1.0f / 23.0f);
    r[1] = (float)((n % 24) - (m % 24)) * (1.0f / 23.0f);
    float v[2][6];
    bases6(r[0], v[0]);
    bases6(r[1], v[1]);
#pragma unroll
    for (int h = 0; h < NHEADS; h++) {
        float s = 0.f;
#pragma unroll
        for (int i = 0; i < 2; i++) {
            s += rb[h * 2 + i] * r[i];
#pragma unroll
            for (int g = 0; g < 6; g++) s += rs[(h * 2 + i) * 6 + g] * v[i][g];
        }
        Bias[(size_t)h * NTOK * NTOK + idx] = s;
    }
}

// ---------------- MFMA flash attention ----------------
// grid (18, 8, 8); 256 thr; 32 q-rows/block. QKV bf16 (T,768). O fp32 (T,256).
__global__ __launch_bounds__(256) void k_attn2(const unsigned short* __restrict__ QKV,
                                               const float* __restrict__ Bias,
                                               float* __restrict__ O) {
    const int b = blockIdx.z, h = blockIdx.y, n0 = blockIdx.x * 32;
    const int tid = threadIdx.x, l = tid & 63, w = tid >> 6;
    const int rh = (w & 1) * 16;   // row-half
    const int kh = (w >> 1) * 16;  // key/d subgroup
    __shared__ unsigned short Ps[2][32 * 40];
    __shared__ float red[4][16];
    const float scale = 0.17677669529663687f;

    bf8s qf = *(const bf8s*)(QKV + (size_t)(b * NTOK + n0 + rh + (l & 15)) * 768 + h * 32 + (l >> 4) * 8);

    f4 s[18];
#pragma unroll
    for (int kc = 0; kc < 18; kc++) {
        bf8s kf = *(const bf8s*)(QKV + (size_t)(b * NTOK + kc * 32 + kh + (l & 15)) * 768 + 256 + h * 32 + (l >> 4) * 8);
        f4 z = {0.f, 0.f, 0.f, 0.f};
        s[kc] = mfma16(qf, kf, z);
    }

    const int r0 = n0 + rh + (l >> 4) * 4;
    float mx[4] = {-1e30f, -1e30f, -1e30f, -1e30f};
#pragma unroll
    for (int kc = 0; kc < 18; kc++)
#pragma unroll
        for (int j = 0; j < 4; j++) {
            float v = s[kc][j] * scale + Bias[((size_t)h * NTOK + r0 + j) * NTOK + kc * 32 + kh + (l & 15)];
            s[kc][j] = v;
            mx[j] = fmaxf(mx[j], v);
        }
#pragma unroll
    for (int j = 0; j < 4; j++)
#pragma unroll
        for (int m = 1; m < 16; m <<= 1) mx[j] = fmaxf(mx[j], __shfl_xor(mx[j], m));
    if ((l & 15) == 0) {
#pragma unroll
        for (int j = 0; j < 4; j++) red[w][(l >> 4) * 4 + j] = mx[j];
    }
    __syncthreads();
#pragma unroll
    for (int j = 0; j < 4; j++) mx[j] = fmaxf(mx[j], red[w ^ 2][(l >> 4) * 4 + j]);
    __syncthreads();
    float sm[4] = {0.f, 0.f, 0.f, 0.f};
#pragma unroll
    for (int kc = 0; kc < 18; kc++)
#pragma unroll
        for (int j = 0; j < 4; j++) {
            float p = __expf(s[kc][j] - mx[j]);
            s[kc][j] = p;
            sm[j] += p;
        }
#pragma unroll
    for (int j = 0; j < 4; j++)
#pragma unroll
        for (int m = 1; m < 16; m <<= 1) sm[j] += __shfl_xor(sm[j], m);
    if ((l & 15) == 0) {
#pragma unroll
        for (int j = 0; j < 4; j++) red[w][(l >> 4) * 4 + j] = sm[j];
    }
    __syncthreads();
#pragma unroll
    for (int j = 0; j < 4; j++) sm[j] = 1.f / (sm[j] + red[w ^ 2][(l >> 4) * 4 + j]);

    f4 oacc = {0.f, 0.f, 0.f, 0.f};
#pragma unroll
    for (int kc = 0; kc < 18; kc++) {
#pragma unroll
        for (int j = 0; j < 4; j++)
            Ps[kc & 1][(rh + (l >> 4) * 4 + j) * 40 + kh + (l & 15)] = f2bf(s[kc][j] * sm[j]);
        __syncthreads();
        bf8s pf = *(const bf8s*)&Ps[kc & 1][(rh + (l & 15)) * 40 + (l >> 4) * 8];
        bf8s vf;
#pragma unroll
        for (int j = 0; j < 8; j++)
            vf[j] = (short)QKV[(size_t)(b * NTOK + kc * 32 + (l >> 4) * 8 + j) * 768 + 512 + h * 32 + kh + (l & 15)];
        oacc = mfma16(pf, vf, oacc);
    }
#pragma unroll
    for (int j = 0; j < 4; j++)
        O[(size_t)(b * NTOK + n0 + rh + (l >> 4) * 4 + j) * CDIM + h * 32 + kh + (l & 15)] = oacc[j];
}

// ---------------- layernorm (+residual) ----------------
__global__ __launch_bounds__(256) void k_ln_add(const float* __restrict__ Xin,
                                                const float* __restrict__ SE,
                                                const float* __restrict__ g,
                                                const float* __restrict__ bb,
                                                float* __restrict__ Out) {
    int t = blockIdx.x, c = threadIdx.x;
    float v = Xin[t * 256 + c];
    float s1 = v, s2 = v * v;
#pragma unroll
    for (int off = 32; off; off >>= 1) { s1 += __shfl_xor(s1, off); s2 += __shfl_xor(s2, off); }
    __shared__ float p1[4], p2[4];
    int wv_ = c >> 6, ln = c & 63;
    if (ln == 0) { p1[wv_] = s1; p2[wv_] = s2; }
    __syncthreads();
    s1 = p1[0] + p1[1] + p1[2] + p1[3];
    s2 = p2[0] + p2[1] + p2[2] + p2[3];
    float m = s1 * (1.f / 256.f);
    float var = s2 * (1.f / 256.f) - m * m;
    float y = (v - m) * rsqrtf(var + 1e-5f) * g[c] + bb[c];
    Out[t * 256 + c] = SE[t * 256 + c] + y;
}

__global__ __launch_bounds__(256) void k_ln_gelu(const float* __restrict__ Xin,
                                                 const float* __restrict__ g,
                                                 const float* __restrict__ bb,
                                                 float* __restrict__ Out) {
    int t = blockIdx.x, c = threadIdx.x;
    float v = Xin[t * 256 + c];
    float s1 = v, s2 = v * v;
#pragma unroll
    for (int off = 32; off; off >>= 1) { s1 += __shfl_xor(s1, off); s2 += __shfl_xor(s2, off); }
    __shared__ float p1[4], p2[4];
    int wv_ = c >> 6, ln = c & 63;
    if (ln == 0) { p1[wv_] = s1; p2[wv_] = s2; }
    __syncthreads();
    s1 = p1[0] + p1[1] + p1[2] + p1[3];
    s2 = p2[0] + p2[1] + p2[2] + p2[3];
    float m = s1 * (1.f / 256.f);
    float var = s2 * (1.f / 256.f) - m * m;
    float y = (v - m) * rsqrtf(var + 1e-5f) * g[c] + bb[c];
    Out[t * 256 + c] = gelu_f(y);
}

// ---------------- mean pool ----------------
__global__ __launch_bounds__(256) void k_meanpool(const float* __restrict__ X,
                                                  float* __restrict__ si, int colofs) {
    int idx = blockIdx.x * 256 + threadIdx.x;
    if (idx >= BB * CDIM) return;
    int b = idx >> 8, c = idx & 255;
    float s = 0.f;
    for (int n = 0; n < NTOK; n++) s += X[(size_t)(b * NTOK + n) * CDIM + c];
    si[b * 512 + colofs + c] = s * (1.f / 576.f);
}

// ---------------- head: fp32 expand + small KAN ----------------
__global__ __launch_bounds__(256) void k_expand(const float* __restrict__ x,
                                                float* __restrict__ bases, int total) {
    int idx = blockIdx.x * 256 + threadIdx.x;
    if (idx >= total) return;
    float b6[6];
    bases6(x[idx], b6);
#pragma unroll
    for (int g = 0; g < 6; g++) bases[idx * 6 + g] = b6[g];
}

__global__ __launch_bounds__(64) void k_small_kan(const float* __restrict__ A1, int K1,
                                                  const float* __restrict__ A2, int K2,
                                                  const float* __restrict__ W1,
                                                  const float* __restrict__ W2,
                                                  float* __restrict__ out, int NN, int act) {
    int o = blockIdx.x, t = blockIdx.y, ln = threadIdx.x;
    float s = 0.f;
    for (int k = ln; k < K1; k += 64) s += A1[t * K1 + k] * W1[o * K1 + k];
    for (int k = ln; k < K2; k += 64) s += A2[t * K2 + k] * W2[o * K2 + k];
#pragma unroll
    for (int off = 32; off; off >>= 1) s += __shfl_xor(s, off);
    if (ln == 0) {
        if (act == 1) s = gelu_f(s);
        else if (act == 2) s = 1.f / (1.f + __expf(-s));
        out[t * NN + o] = s;
    }
}

__global__ void k_fi(const float* __restrict__ si, const float* __restrict__ wv,
                     float* __restrict__ fi) {
    int idx = blockIdx.x * 256 + threadIdx.x;
    if (idx >= BB * 512) return;
    int b = idx >> 9, i = idx & 511;
    float w = wv[b];
    fi[idx] = si[idx] * (i < 256 ? w : 1.f - w);
}

extern "C" void kernel_launch(void* const* d_in, const int* in_sizes, int n_in,
                              void* d_out, int out_size, void* d_ws, size_t ws_size,
                              hipStream_t stream) {
    (void)in_sizes; (void)n_in; (void)out_size; (void)ws_size;
    const float* sat_f = (const float*)d_in[0];
    const float* uav_f = (const float*)d_in[1];
    const float* s_qb  = (const float*)d_in[2];
    const float* s_qs  = (const float*)d_in[3];
    const float* s_rb  = (const float*)d_in[4];
    const float* s_rs  = (const float*)d_in[5];
    const float* u_qb  = (const float*)d_in[6];
    const float* u_qs  = (const float*)d_in[7];
    const float* u_rb  = (const float*)d_in[8];
    const float* u_rs  = (const float*)d_in[9];
    const float* r_w1b = (const float*)d_in[10];
    const float* r_w1s = (const float*)d_in[11];
    const float* r_w2b = (const float*)d_in[12];
    const float* r_w2s = (const float*)d_in[13];
    const float* r_lng = (const float*)d_in[14];
    const float* r_lnb = (const float*)d_in[15];
    const float* m_w1b = (const float*)d_in[16];
    const float* m_w1s = (const float*)d_in[17];
    const float* m_w2b = (const float*)d_in[18];
    const float* m_w2s = (const float*)d_in[19];
    const float* m_w3b = (const float*)d_in[20];
    const float* m_w3s = (const float*)d_in[21];
    const float* f_wb  = (const float*)d_in[22];
    const float* f_ws  = (const float*)d_in[23];
    const float* f_lng = (const float*)d_in[24];
    const float* f_lnb = (const float*)d_in[25];

    char* p = (char*)d_ws;
    auto alloc = [&](size_t bytes) { char* r = p; p += (bytes + 255) & ~(size_t)255; return r; };
    float* xs    = (float*)alloc((size_t)TT * 256 * 4);
    float* xu    = (float*)alloc((size_t)TT * 256 * 4);
    unsigned short* AEXP = (unsigned short*)alloc((size_t)TT * 3072 * 2);
    unsigned short* QKVb = (unsigned short*)alloc((size_t)TT * 768 * 2);
    float* BIAS  = (float*)alloc((size_t)8 * NTOK * NTOK * 4);
    float* OB    = (float*)alloc((size_t)TT * 256 * 4);
    float* SEb   = (float*)alloc((size_t)TT * 256 * 4);
    float* H2    = (float*)alloc((size_t)TT * 256 * 4);
    unsigned short* H1b  = (unsigned short*)alloc((size_t)TT * 1024 * 2);
    unsigned short* Wq   = (unsigned short*)alloc((size_t)768 * 1792 * 2);
    unsigned short* Wp   = (unsigned short*)alloc((size_t)256 * 1792 * 2);
    unsigned short* Ww1  = (unsigned short*)alloc((size_t)1024 * 1792 * 2);
    unsigned short* Ww2b = (unsigned short*)alloc((size_t)256 * 1024 * 2);
    unsigned short* Ww2s0 = (unsigned short*)alloc((size_t)256 * 3072 * 2);
    unsigned short* Ww2s1 = (unsigned short*)alloc((size_t)256 * 3072 * 2);
    float* si    = (float*)alloc(BB * 512 * 4);
    float* SB    = (float*)alloc((size_t)BB * 1024 * 6 * 4);
    float* h1f   = (float*)alloc(BB * 1024 * 4);
    float* h2f   = (float*)alloc(BB * 64 * 4);
    float* wv    = (float*)alloc(BB * 4);
    float* fi    = (float*)alloc(BB * 512 * 4);
    float* ftmp  = (float*)alloc(BB * 256 * 4);

    k_transpose<<<TT, 256, 0, stream>>>(sat_f, xs);
    k_transpose<<<TT, 256, 0, stream>>>(uav_f, xu);

    for (int l = 0; l < 3; l++) {
        for (int st2 = 0; st2 < 2; st2++) {
            float* X = st2 ? xu : xs;
            const float* qb = (st2 ? u_qb : s_qb) + (size_t)l * 4 * 256 * 256;
            const float* qs = (st2 ? u_qs : s_qs) + (size_t)l * 4 * 256 * 256 * 6;
            const float* rb = (st2 ? u_rb : s_rb) + l * 16;
            const float* rs = (st2 ? u_rs : s_rs) + l * 96;

            // weight repacks (bf16)
            k_pack_cat<<<(768 * 1792 + 255) / 256, 256, 0, stream>>>(qb, qs, Wq, 768, 256);
            k_pack_cat<<<(256 * 1792 + 255) / 256, 256, 0, stream>>>(
                qb + 3 * 65536, qs + 3 * 393216, Wp, 256, 256);
            k_pack_cat<<<(1024 * 1792 + 255) / 256, 256, 0, stream>>>(
                r_w1b + (size_t)l * 262144, r_w1s + (size_t)l * 1572864, Ww1, 1024, 256);
            k_pack_str<<<(256 * 1024 + 255) / 256, 256, 0, stream>>>(
                r_w2b + (size_t)l * 262144, Ww2b, 256, 1024, 1024, 0);
            k_pack_str<<<(256 * 3072 + 255) / 256, 256, 0, stream>>>(
                r_w2s + (size_t)l * 1572864, Ww2s0, 256, 3072, 6144, 0);
            k_pack_str<<<(256 * 3072 + 255) / 256, 256, 0, stream>>>(
                r_w2s + (size_t)l * 1572864, Ww2s1, 256, 3072, 6144, 3072);

            // QKV
            k_expand7<<<(TT * 256 + 255) / 256, 256, 0, stream>>>(X, AEXP, 256, TT * 256);
            mgemm<128, 128, 0, 2><<<dim3(768 / 128, TT / 128), 256, 0, stream>>>(
                AEXP, Wq, (void*)QKVb, 768, 1792);
            // bias + attention
            k_bias<<<(NTOK * NTOK + 255) / 256, 256, 0, stream>>>(rb, rs, BIAS);
            k_attn2<<<dim3(18, NHEADS, BB), 256, 0, stream>>>(QKVb, BIAS, OB);
            // proj
            k_expand7<<<(TT * 256 + 255) / 256, 256, 0, stream>>>(OB, AEXP, 256, TT * 256);
            mgemm<128, 64, 0, 0><<<dim3(256 / 64, TT / 128), 256, 0, stream>>>(
                AEXP, Wp, (void*)SEb, 256, 1792);
            // refine w1 (+gelu, bf16 out)
            k_expand7<<<(TT * 256 + 255) / 256, 256, 0, stream>>>(SEb, AEXP, 256, TT * 256);
            mgemm<128, 128, 1, 2><<<dim3(1024 / 128, TT / 128), 256, 0, stream>>>(
                AEXP, Ww1, (void*)H1b, 1024, 1792);
            // refine w2: base pass + two spline passes (accumulate)
            mgemm<64, 64, 0, 0><<<dim3(256 / 64, TT / 64), 256, 0, stream>>>(
                H1b, Ww2b, (void*)H2, 256, 1024);
            k_ex_half<<<(TT * 512 + 255) / 256, 256, 0, stream>>>(H1b, AEXP, 0);
            mgemm<64, 64, 0, 1><<<dim3(256 / 64, TT / 64), 256, 0, stream>>>(
                AEXP, Ww2s0, (void*)H2, 256, 3072);
            k_ex_half<<<(TT * 512 + 255) / 256, 256, 0, stream>>>(H1b, AEXP, 512);
            mgemm<64, 64, 0, 1><<<dim3(256 / 64, TT / 64), 256, 0, stream>>>(
                AEXP, Ww2s1, (void*)H2, 256, 3072);
            // LN + residual -> X
            k_ln_add<<<TT, 256, 0, stream>>>(H2, SEb, r_lng + l * 256, r_lnb + l * 256, X);
        }
    }

    // final head (fp32, tiny)
    k_meanpool<<<8, 256, 0, stream>>>(xs, si, 0);
    k_meanpool<<<8, 256, 0, stream>>>(xu, si, 256);
    k_expand<<<(BB * 512 + 255) / 256, 256, 0, stream>>>(si, SB, BB * 512);
    k_small_kan<<<dim3(1024, BB), 64, 0, stream>>>(si, 512, SB, 3072, m_w1b, m_w1s, h1f, 1024, 1);
    k_expand<<<(BB * 1024 + 255) / 256, 256, 0, stream>>>(h1f, SB, BB * 1024);
    k_small_kan<<<dim3(64, BB), 64, 0, stream>>>(h1f, 1024, SB, 6144, m_w2b, m_w2s, h2f, 64, 1);
    k_expand<<<(BB * 64 + 255) / 256, 256, 0, stream>>>(h2f, SB, BB * 64);
    k_small_kan<<<dim3(1, BB), 64, 0, stream>>>(h2f, 64, SB, 384, m_w3b, m_w3s, wv, 1, 2);
    k_fi<<<16, 256, 0, stream>>>(si, wv, fi);
    k_expand<<<(BB * 512 + 255) / 256, 256, 0, stream>>>(fi, SB, BB * 512);
    k_small_kan<<<dim3(256, BB), 64, 0, stream>>>(fi, 512, SB, 3072, f_wb, f_ws, ftmp, 256, 0);
    k_ln_gelu<<<8, 256, 0, stream>>>(ftmp, f_lng, f_lnb, (float*)d_out);
}

// Round 3
// 1535.390 us; speedup vs baseline: 9.4326x; 1.4184x over previous
//
#include <hip/hip_runtime.h>
#include <math.h>

#define TT      4608   // tokens per stream (B*N)
#define BB      8
#define NTOK    576
#define CDIM    256
#define NHEADS  8
#define HIDDIM  1024

typedef __attribute__((ext_vector_type(8))) short bf8s;   // 8 bf16
typedef __attribute__((ext_vector_type(4))) float f4;
typedef __attribute__((ext_vector_type(4))) short sv4;
typedef __attribute__((ext_vector_type(8))) short sv8;

__device__ __forceinline__ f4 mfma16(bf8s a, bf8s b, f4 c) {
    return __builtin_amdgcn_mfma_f32_16x16x32_bf16(a, b, c, 0, 0, 0);
}

__device__ __forceinline__ unsigned short f2bf(float x) {
    union { float f; unsigned int u; } v; v.f = x;
    unsigned int r = v.u + 0x7FFFu + ((v.u >> 16) & 1u);
    return (unsigned short)(r >> 16);
}
__device__ __forceinline__ float bf2f(unsigned short h) {
    union { unsigned int u; float f; } v; v.u = ((unsigned int)h) << 16;
    return v.f;
}

__device__ __forceinline__ float gelu_f(float x) {
    return 0.5f * x * (1.0f + erff(x * 0.70710678118654752f));
}

__device__ __forceinline__ void bases6(float v, float* out) {
    float e[6]; float s = 0.f;
#pragma unroll
    for (int g = 0; g < 6; g++) {
        float d = v - (-1.0f + 0.4f * g);
        e[g] = __expf(-d * d * 12.5f);
        s += e[g];
    }
    float inv = 1.f / (s + 1e-8f);
#pragma unroll
    for (int g = 0; g < 6; g++) out[g] = e[g] * inv;
}

__device__ __forceinline__ void gload16(const void* g, void* l) {
    __builtin_amdgcn_global_load_lds(
        (const __attribute__((address_space(1))) unsigned int*)g,
        (__attribute__((address_space(3))) unsigned int*)l, 16, 0, 0);
}

// ---------------- transpose (B,C,H,W) -> (T, C) fp32 ----------------
__global__ __launch_bounds__(256) void k_transpose(const float* __restrict__ in,
                                                   float* __restrict__ out) {
    int idx = blockIdx.x * 256 + threadIdx.x;
    if (idx >= TT * CDIM) return;
    int t = idx >> 8, c = idx & 255;
    int b = t / NTOK, n = t % NTOK;
    out[idx] = in[(b * CDIM + c) * NTOK + n];
}

// ---------------- expand: fp32 x (Mr,256) -> bf16 [x | bases] (Mr, 1792) ----------------
__global__ __launch_bounds__(256) void k_expand7(const float* __restrict__ x,
                                                 unsigned short* __restrict__ out, int Mr) {
    int idx = blockIdx.x * 256 + threadIdx.x;
    if (idx >= Mr * 64) return;
    int t = idx >> 6, i4 = (idx & 63) << 2;
    float4 xv = *(const float4*)(x + (size_t)t * 256 + i4);
    float xa[4] = {xv.x, xv.y, xv.z, xv.w};
    size_t ro = (size_t)t * 1792;
    sv4 bsv;
    float bas[4][6];
#pragma unroll
    for (int u = 0; u < 4; u++) { bsv[u] = (short)f2bf(xa[u]); bases6(xa[u], bas[u]); }
    *(sv4*)(out + ro + i4) = bsv;
    unsigned short tmp[24];
#pragma unroll
    for (int u = 0; u < 4; u++)
#pragma unroll
        for (int g = 0; g < 6; g++) tmp[u * 6 + g] = f2bf(bas[u][g]);
    sv8* dst = (sv8*)(out + ro + 256 + (size_t)i4 * 6);
#pragma unroll
    for (int k = 0; k < 3; k++) dst[k] = *(sv8*)&tmp[k * 8];
}

// ---------------- expand half of H1 (bf16 row-stride 1024) -> bases (TT, 3072) ----------------
__global__ __launch_bounds__(256) void k_ex_half(const unsigned short* __restrict__ h1,
                                                 unsigned short* __restrict__ out, int c0) {
    int idx = blockIdx.x * 256 + threadIdx.x;
    if (idx >= TT * 128) return;
    int t = idx >> 7, i4 = (idx & 127) << 2;
    sv4 hv = *(const sv4*)(h1 + (size_t)t * 1024 + c0 + i4);
    unsigned short tmp[24];
#pragma unroll
    for (int u = 0; u < 4; u++) {
        float b6[6]; bases6(bf2f((unsigned short)hv[u]), b6);
#pragma unroll
        for (int g = 0; g < 6; g++) tmp[u * 6 + g] = f2bf(b6[g]);
    }
    sv8* dst = (sv8*)(out + (size_t)t * 3072 + (size_t)i4 * 6);
#pragma unroll
    for (int k = 0; k < 3; k++) dst[k] = *(sv8*)&tmp[k * 8];
}

// ---------------- pack one layer's weights (both streams) fp32 -> bf16 ----------------
__global__ __launch_bounds__(256) void k_pack_layer(
    const float* __restrict__ sqb, const float* __restrict__ sqs,
    const float* __restrict__ uqb, const float* __restrict__ uqs,
    const float* __restrict__ w1b, const float* __restrict__ w1s,
    const float* __restrict__ w2b, const float* __restrict__ w2s,
    unsigned short* __restrict__ Wq, unsigned short* __restrict__ Wp,
    unsigned short* __restrict__ Ww1, unsigned short* __restrict__ Ww2b,
    unsigned short* __restrict__ Ww2s) {
    const size_t nWq = 1376256, nWp = 458752, nWw1 = 1835008, nWw2b = 262144;
    size_t idx = ((size_t)blockIdx.x * 256 + threadIdx.x) * 4;
    float4 v; unsigned short* dst;
    if (idx < 2 * nWq) {
        int s = idx >= nWq; size_t off = idx - (size_t)s * nWq;
        const float* base = s ? uqb : sqb; const float* spl = s ? uqs : sqs;
        int r = (int)(off / 1792), c = (int)(off % 1792);
        v = (c < 256) ? *(const float4*)(base + (size_t)r * 256 + c)
                      : *(const float4*)(spl + (size_t)r * 1536 + (c - 256));
        dst = Wq + s * nWq + off;
    } else if (idx < 2 * nWq + 2 * nWp) {
        size_t off2 = idx - 2 * nWq; int s = off2 >= nWp; size_t off = off2 - (size_t)s * nWp;
        const float* base = (s ? uqb : sqb) + 3 * 65536;
        const float* spl  = (s ? uqs : sqs) + 3 * 393216;
        int r = (int)(off / 1792), c = (int)(off % 1792);
        v = (c < 256) ? *(const float4*)(base + (size_t)r * 256 + c)
                      : *(const float4*)(spl + (size_t)r * 1536 + (c - 256));
        dst = Wp + s * nWp + off;
    } else if (idx < 2 * nWq + 2 * nWp + nWw1) {
        size_t off = idx - 2 * nWq - 2 * nWp;
        int r = (int)(off / 1792), c = (int)(off % 1792);
        v = (c < 256) ? *(const float4*)(w1b + (size_t)r * 256 + c)
                      : *(const float4*)(w1s + (size_t)r * 1536 + (c - 256));
        dst = Ww1 + off;
    } else if (idx < 2 * nWq + 2 * nWp + nWw1 + nWw2b) {
        size_t off = idx - 2 * nWq - 2 * nWp - nWw1;
        v = *(const float4*)(w2b + off);
        dst = Ww2b + off;
    } else {
        size_t off = idx - 2 * nWq - 2 * nWp - nWw1 - nWw2b;
        v = *(const float4*)(w2s + off);
        dst = Ww2s + off;
    }
    sv4 o;
    o[0] = (short)f2bf(v.x); o[1] = (short)f2bf(v.y);
    o[2] = (short)f2bf(v.z); o[3] = (short)f2bf(v.w);
    *(sv4*)dst = o;
}

// ---------------- bf16 MFMA GEMM, dbuf LDS, XCD-swizzled, grouped weights ----------------
// A (M,K) bf16 rm (row stride K); W (NN,K) bf16 rm row stride WLD; rows >= groupRows use W1.
// CMODE: 0 = store f32, 1 = += f32, 2 = store bf16.  Launch: 1D grid of gx*gy blocks.
template<int BM, int BN, int ACT, int CMODE>
__global__ __launch_bounds__(256) void mgemm(const unsigned short* __restrict__ A,
                                             const unsigned short* __restrict__ W0,
                                             const unsigned short* __restrict__ W1,
                                             void* __restrict__ Cv, int NN, int K,
                                             int WLD, int gx, int groupRows) {
    constexpr int MF = BM / 32;
    constexpr int NF = BN / 32;
    __shared__ unsigned short As[2][BM * 32];
    __shared__ unsigned short Bs[2][BN * 32];
    // bijective XCD swizzle (m204)
    int nwg = gridDim.x, orig = blockIdx.x;
    int q = nwg >> 3, r = nwg & 7;
    int xcd = orig & 7, loc = orig >> 3;
    int wg = (xcd < r ? xcd * (q + 1) : r * (q + 1) + (xcd - r) * q) + loc;
    int bx = wg % gx, by = wg / gx;
    const int bm = by * BM, bn = bx * BN;
    const unsigned short* W = (bm >= groupRows) ? W1 : W0;
    const int tid = threadIdx.x, l = tid & 63, w = tid >> 6;
    const int wr = w >> 1, wc = w & 1;
    const int rowA = l >> 2, colb = (l & 3) * 8;
    f4 acc[MF][NF];
#pragma unroll
    for (int m = 0; m < MF; m++)
#pragma unroll
        for (int n = 0; n < NF; n++) acc[m][n] = (f4){0.f, 0.f, 0.f, 0.f};

    auto stage = [&](int buf, int kt) {
#pragma unroll
        for (int it = 0; it < BM / 64; it++) {
            int rr = (it * 4 + w) * 16 + rowA;
            gload16(A + (size_t)(bm + rr) * K + kt + colb, (void*)(&As[buf][rr * 32 + colb]));
        }
#pragma unroll
        for (int it = 0; it < BN / 64; it++) {
            int rr = (it * 4 + w) * 16 + rowA;
            gload16(W + (size_t)(bn + rr) * WLD + kt + colb, (void*)(&Bs[buf][rr * 32 + colb]));
        }
    };
    stage(0, 0);
    __syncthreads();
    const int nt = K / 32;
    for (int t = 0; t < nt; t++) {
        int cur = t & 1;
        if (t + 1 < nt) stage(cur ^ 1, (t + 1) * 32);
        bf8s af[MF], bfr[NF];
#pragma unroll
        for (int m = 0; m < MF; m++)
            af[m] = *(const bf8s*)&As[cur][(wr * (BM / 2) + m * 16 + (l & 15)) * 32 + (l >> 4) * 8];
#pragma unroll
        for (int n = 0; n < NF; n++)
            bfr[n] = *(const bf8s*)&Bs[cur][(wc * (BN / 2) + n * 16 + (l & 15)) * 32 + (l >> 4) * 8];
#pragma unroll
        for (int m = 0; m < MF; m++)
#pragma unroll
            for (int n = 0; n < NF; n++)
                acc[m][n] = mfma16(af[m], bfr[n], acc[m][n]);
        __syncthreads();
    }
#pragma unroll
    for (int m = 0; m < MF; m++)
#pragma unroll
        for (int n = 0; n < NF; n++)
#pragma unroll
            for (int j = 0; j < 4; j++) {
                int row = bm + wr * (BM / 2) + m * 16 + (l >> 4) * 4 + j;
                int col = bn + wc * (BN / 2) + n * 16 + (l & 15);
                float v = acc[m][n][j];
                if (ACT == 1) v = gelu_f(v);
                size_t o = (size_t)row * NN + col;
                if (CMODE == 0)      ((float*)Cv)[o] = v;
                else if (CMODE == 1) ((float*)Cv)[o] += v;
                else                 ((unsigned short*)Cv)[o] = f2bf(v);
            }
}

// ---------------- relative-position bias (nb, NH, N, N) fp32 ----------------
__global__ __launch_bounds__(256) void k_bias(const float* __restrict__ rb0,
                                              const float* __restrict__ rs0,
                                              const float* __restrict__ rb1,
                                              const float* __restrict__ rs1,
                                              float* __restrict__ Bias) {
    int sidx = blockIdx.y;
    const float* rb = sidx ? rb1 : rb0;
    const float* rs = sidx ? rs1 : rs0;
    float* B = Bias + (size_t)sidx * NHEADS * NTOK * NTOK;
    int idx = blockIdx.x * 256 + threadIdx.x;
    if (idx >= NTOK * NTOK) return;
    int n = idx / NTOK, m = idx % NTOK;
    float r[2];
    r[0] = (float)((n / 24) - (m / 24)) * (1.0f / 23.0f);
    r[1] = (float)((n % 24) - (m % 24)) * (1.0f / 23.0f);
    float v[2][6];
    bases6(r[0], v[0]);
    bases6(r[1], v[1]);
#pragma unroll
    for (int h = 0; h < NHEADS; h++) {
        float s = 0.f;
#pragma unroll
        for (int i = 0; i < 2; i++) {
            s += rb[h * 2 + i] * r[i];
#pragma unroll
            for (int g = 0; g < 6; g++) s += rs[(h * 2 + i) * 6 + g] * v[i][g];
        }
        B[(size_t)h * NTOK * NTOK + idx] = s;
    }
}

// ---------------- MFMA flash attention; grid (18, 8, nb*8) ----------------
__global__ __launch_bounds__(256) void k_attn2(const unsigned short* __restrict__ QKV,
                                               const float* __restrict__ Bias,
                                               float* __restrict__ O) {
    const int z = blockIdx.z, h = blockIdx.y, n0 = blockIdx.x * 32;
    const int tid = threadIdx.x, l = tid & 63, w = tid >> 6;
    const int rh = (w & 1) * 16;
    const int kh = (w >> 1) * 16;
    __shared__ unsigned short Ps[2][32 * 40];
    __shared__ float red[4][16];
    const float scale = 0.17677669529663687f;
    const size_t rowbase = (size_t)z * NTOK;
    const float* Bh = Bias + ((size_t)(z >> 3) * NHEADS + h) * NTOK * NTOK;

    bf8s qf = *(const bf8s*)(QKV + (rowbase + n0 + rh + (l & 15)) * 768 + h * 32 + (l >> 4) * 8);

    f4 s[18];
#pragma unroll
    for (int kc = 0; kc < 18; kc++) {
        bf8s kf = *(const bf8s*)(QKV + (rowbase + kc * 32 + kh + (l & 15)) * 768 + 256 + h * 32 + (l >> 4) * 8);
        f4 zz = {0.f, 0.f, 0.f, 0.f};
        s[kc] = mfma16(qf, kf, zz);
    }

    const int r0 = n0 + rh + (l >> 4) * 4;
    float mx[4] = {-1e30f, -1e30f, -1e30f, -1e30f};
#pragma unroll
    for (int kc = 0; kc < 18; kc++)
#pragma unroll
        for (int j = 0; j < 4; j++) {
            float v = s[kc][j] * scale + Bh[(size_t)(r0 + j) * NTOK + kc * 32 + kh + (l & 15)];
            s[kc][j] = v;
            mx[j] = fmaxf(mx[j], v);
        }
#pragma unroll
    for (int j = 0; j < 4; j++)
#pragma unroll
        for (int m = 1; m < 16; m <<= 1) mx[j] = fmaxf(mx[j], __shfl_xor(mx[j], m));
    if ((l & 15) == 0) {
#pragma unroll
        for (int j = 0; j < 4; j++) red[w][(l >> 4) * 4 + j] = mx[j];
    }
    __syncthreads();
#pragma unroll
    for (int j = 0; j < 4; j++) mx[j] = fmaxf(mx[j], red[w ^ 2][(l >> 4) * 4 + j]);
    __syncthreads();
    float sm[4] = {0.f, 0.f, 0.f, 0.f};
#pragma unroll
    for (int kc = 0; kc < 18; kc++)
#pragma unroll
        for (int j = 0; j < 4; j++) {
            float p = __expf(s[kc][j] - mx[j]);
            s[kc][j] = p;
            sm[j] += p;
        }
#pragma unroll
    for (int j = 0; j < 4; j++)
#pragma unroll
        for (int m = 1; m < 16; m <<= 1) sm[j] += __shfl_xor(sm[j], m);
    if ((l & 15) == 0) {
#pragma unroll
        for (int j = 0; j < 4; j++) red[w][(l >> 4) * 4 + j] = sm[j];
    }
    __syncthreads();
#pragma unroll
    for (int j = 0; j < 4; j++) sm[j] = 1.f / (sm[j] + red[w ^ 2][(l >> 4) * 4 + j]);

    f4 oacc = {0.f, 0.f, 0.f, 0.f};
#pragma unroll
    for (int kc = 0; kc < 18; kc++) {
#pragma unroll
        for (int j = 0; j < 4; j++)
            Ps[kc & 1][(rh + (l >> 4) * 4 + j) * 40 + kh + (l & 15)] = f2bf(s[kc][j] * sm[j]);
        __syncthreads();
        bf8s pf = *(const bf8s*)&Ps[kc & 1][(rh + (l & 15)) * 40 + (l >> 4) * 8];
        bf8s vf;
#pragma unroll
        for (int j = 0; j < 8; j++)
            vf[j] = (short)QKV[(rowbase + kc * 32 + (l >> 4) * 8 + j) * 768 + 512 + h * 32 + kh + (l & 15)];
        oacc = mfma16(pf, vf, oacc);
    }
#pragma unroll
    for (int j = 0; j < 4; j++)
        O[(rowbase + n0 + rh + (l >> 4) * 4 + j) * CDIM + h * 32 + kh + (l & 15)] = oacc[j];
}

// ---------------- layernorm (+residual) ----------------
__global__ __launch_bounds__(256) void k_ln_add(const float* __restrict__ Xin,
                                                const float* __restrict__ SE,
                                                const float* __restrict__ g,
                                                const float* __restrict__ bb,
                                                float* __restrict__ Out) {
    int t = blockIdx.x, c = threadIdx.x;
    float v = Xin[(size_t)t * 256 + c];
    float s1 = v, s2 = v * v;
#pragma unroll
    for (int off = 32; off; off >>= 1) { s1 += __shfl_xor(s1, off); s2 += __shfl_xor(s2, off); }
    __shared__ float p1[4], p2[4];
    int wv_ = c >> 6, ln = c & 63;
    if (ln == 0) { p1[wv_] = s1; p2[wv_] = s2; }
    __syncthreads();
    s1 = p1[0] + p1[1] + p1[2] + p1[3];
    s2 = p2[0] + p2[1] + p2[2] + p2[3];
    float m = s1 * (1.f / 256.f);
    float var = s2 * (1.f / 256.f) - m * m;
    float y = (v - m) * rsqrtf(var + 1e-5f) * g[c] + bb[c];
    Out[(size_t)t * 256 + c] = SE[(size_t)t * 256 + c] + y;
}

__global__ __launch_bounds__(256) void k_ln_gelu(const float* __restrict__ Xin,
                                                 const float* __restrict__ g,
                                                 const float* __restrict__ bb,
                                                 float* __restrict__ Out) {
    int t = blockIdx.x, c = threadIdx.x;
    float v = Xin[t * 256 + c];
    float s1 = v, s2 = v * v;
#pragma unroll
    for (int off = 32; off; off >>= 1) { s1 += __shfl_xor(s1, off); s2 += __shfl_xor(s2, off); }
    __shared__ float p1[4], p2[4];
    int wv_ = c >> 6, ln = c & 63;
    if (ln == 0) { p1[wv_] = s1; p2[wv_] = s2; }
    __syncthreads();
    s1 = p1[0] + p1[1] + p1[2] + p1[3];
    s2 = p2[0] + p2[1] + p2[2] + p2[3];
    float m = s1 * (1.f / 256.f);
    float var = s2 * (1.f / 256.f) - m * m;
    float y = (v - m) * rsqrtf(var + 1e-5f) * g[c] + bb[c];
    Out[t * 256 + c] = gelu_f(y);
}

// ---------------- mean pool ----------------
__global__ __launch_bounds__(256) void k_meanpool(const float* __restrict__ X,
                                                  float* __restrict__ si, int colofs) {
    int idx = blockIdx.x * 256 + threadIdx.x;
    if (idx >= BB * CDIM) return;
    int b = idx >> 8, c = idx & 255;
    float s = 0.f;
    for (int n = 0; n < NTOK; n++) s += X[(size_t)(b * NTOK + n) * CDIM + c];
    si[b * 512 + colofs + c] = s * (1.f / 576.f);
}

// ---------------- head: fp32 expand + small KAN ----------------
__global__ __launch_bounds__(256) void k_expand(const float* __restrict__ x,
                                                float* __restrict__ bases, int total) {
    int idx = blockIdx.x * 256 + threadIdx.x;
    if (idx >= total) return;
    float b6[6];
    bases6(x[idx], b6);
#pragma unroll
    for (int g = 0; g < 6; g++) bases[idx * 6 + g] = b6[g];
}

__global__ __launch_bounds__(64) void k_small_kan(const float* __restrict__ A1, int K1,
                                                  const float* __restrict__ A2, int K2,
                                                  const float* __restrict__ W1,
                                                  const float* __restrict__ W2,
                                                  float* __restrict__ out, int NN, int act) {
    int o = blockIdx.x, t = blockIdx.y, ln = threadIdx.x;
    float s = 0.f;
    for (int k = ln; k < K1; k += 64) s += A1[t * K1 + k] * W1[o * K1 + k];
    for (int k = ln; k < K2; k += 64) s += A2[t * K2 + k] * W2[o * K2 + k];
#pragma unroll
    for (int off = 32; off; off >>= 1) s += __shfl_xor(s, off);
    if (ln == 0) {
        if (act == 1) s = gelu_f(s);
        else if (act == 2) s = 1.f / (1.f + __expf(-s));
        out[t * NN + o] = s;
    }
}

__global__ void k_fi(const float* __restrict__ si, const float* __restrict__ wv,
                     float* __restrict__ fi) {
    int idx = blockIdx.x * 256 + threadIdx.x;
    if (idx >= BB * 512) return;
    int b = idx >> 9, i = idx & 511;
    float w = wv[b];
    fi[idx] = si[idx] * (i < 256 ? w : 1.f - w);
}

extern "C" void kernel_launch(void* const* d_in, const int* in_sizes, int n_in,
                              void* d_out, int out_size, void* d_ws, size_t ws_size,
                              hipStream_t stream) {
    (void)in_sizes; (void)n_in; (void)out_size;
    const float* sat_f = (const float*)d_in[0];
    const float* uav_f = (const float*)d_in[1];
    const float* s_qb  = (const float*)d_in[2];
    const float* s_qs  = (const float*)d_in[3];
    const float* s_rb  = (const float*)d_in[4];
    const float* s_rs  = (const float*)d_in[5];
    const float* u_qb  = (const float*)d_in[6];
    const float* u_qs  = (const float*)d_in[7];
    const float* u_rb  = (const float*)d_in[8];
    const float* u_rs  = (const float*)d_in[9];
    const float* r_w1b = (const float*)d_in[10];
    const float* r_w1s = (const float*)d_in[11];
    const float* r_w2b = (const float*)d_in[12];
    const float* r_w2s = (const float*)d_in[13];
    const float* r_lng = (const float*)d_in[14];
    const float* r_lnb = (const float*)d_in[15];
    const float* m_w1b = (const float*)d_in[16];
    const float* m_w1s = (const float*)d_in[17];
    const float* m_w2b = (const float*)d_in[18];
    const float* m_w2s = (const float*)d_in[19];
    const float* m_w3b = (const float*)d_in[20];
    const float* m_w3s = (const float*)d_in[21];
    const float* f_wb  = (const float*)d_in[22];
    const float* f_ws  = (const float*)d_in[23];
    const float* f_lng = (const float*)d_in[24];
    const float* f_lnb = (const float*)d_in[25];

    const size_t nWq = 1376256, nWp = 458752;

    // workspace planner; nb = streams batched per GEMM (2 if ws allows, else 1)
    float* X; unsigned short* AEXP; unsigned short* QKVb; char* R;
    unsigned short *Wq, *Wp, *Ww1, *Ww2b, *Ww2s;
    float *si, *SB, *h1f, *h2f, *wvv, *fiB, *ftmp;
    size_t OB_OFF = 0, H2_OFF = 0, SEB_OFF = 0;
    auto plan = [&](int nb, bool assign) -> size_t {
        size_t off = 0;
        auto take = [&](size_t bytes) -> char* {
            char* rp = (char*)d_ws + off;
            off = (off + bytes + 255) & ~(size_t)255;
            return rp;
        };
        size_t Mr = (size_t)nb * TT;
        char* p;
        p = take((size_t)2 * TT * 256 * 4);             if (assign) X = (float*)p;
        size_t aexpE = Mr * 1792; if ((size_t)TT * 3072 > aexpE) aexpE = (size_t)TT * 3072;
        p = take(aexpE * 2);                            if (assign) AEXP = (unsigned short*)p;
        p = take(Mr * 768 * 2);                         if (assign) QKVb = (unsigned short*)p;
        size_t biasSz = (size_t)nb * NHEADS * NTOK * NTOK * 4;
        size_t obSz = Mr * 256 * 4, h1Sz = Mr * 1024 * 2, h2Sz = Mr * 256 * 4, seSz = Mr * 256 * 4;
        size_t sebOff = h1Sz + h2Sz; if (biasSz + obSz > sebOff) sebOff = biasSz + obSz;
        if (assign) { OB_OFF = biasSz; H2_OFF = h1Sz; SEB_OFF = sebOff; }
        p = take(sebOff + seSz);                        if (assign) R = p;
        p = take(2 * nWq * 2);                          if (assign) Wq = (unsigned short*)p;
        p = take(2 * nWp * 2);                          if (assign) Wp = (unsigned short*)p;
        p = take((size_t)1835008 * 2);                  if (assign) Ww1 = (unsigned short*)p;
        p = take((size_t)262144 * 2);                   if (assign) Ww2b = (unsigned short*)p;
        p = take((size_t)1572864 * 2);                  if (assign) Ww2s = (unsigned short*)p;
        p = take(BB * 512 * 4);                         if (assign) si = (float*)p;
        p = take((size_t)BB * 1024 * 6 * 4);            if (assign) SB = (float*)p;
        p = take(BB * 1024 * 4);                        if (assign) h1f = (float*)p;
        p = take(BB * 64 * 4);                          if (assign) h2f = (float*)p;
        p = take(64 * 4);                               if (assign) wvv = (float*)p;
        p = take(BB * 512 * 4);                         if (assign) fiB = (float*)p;
        p = take(BB * 256 * 4);                         if (assign) ftmp = (float*)p;
        return off;
    };
    int nb = (ws_size >= plan(2, false)) ? 2 : 1;
    plan(nb, true);

    k_transpose<<<TT, 256, 0, stream>>>(sat_f, X);
    k_transpose<<<TT, 256, 0, stream>>>(uav_f, X + (size_t)TT * 256);

    const int Mr = nb * TT;
    float* BIASp = (float*)R;
    float* OBp   = (float*)(R + OB_OFF);
    unsigned short* H1bp = (unsigned short*)R;
    float* H2p   = (float*)(R + H2_OFF);
    float* SEbp  = (float*)(R + SEB_OFF);

    for (int l = 0; l < 3; l++) {
        // pack this layer's weights (both streams), once
        k_pack_layer<<<7168, 256, 0, stream>>>(
            s_qb + (size_t)l * 262144, s_qs + (size_t)l * 1572864,
            u_qb + (size_t)l * 262144, u_qs + (size_t)l * 1572864,
            r_w1b + (size_t)l * 262144, r_w1s + (size_t)l * 1572864,
            r_w2b + (size_t)l * 262144, r_w2s + (size_t)l * 1572864,
            Wq, Wp, Ww1, Ww2b, Ww2s);

        for (int st0 = 0; st0 < 2; st0 += nb) {
            float* Xs = X + (size_t)st0 * TT * 256;
            // QKV
            k_expand7<<<Mr * 64 / 256, 256, 0, stream>>>(Xs, AEXP, Mr);
            mgemm<128, 128, 0, 2><<<6 * (Mr / 128), 256, 0, stream>>>(
                AEXP, Wq + (size_t)st0 * nWq, Wq + nWq, (void*)QKVb, 768, 1792, 1792, 6, TT);
            // bias + attention
            {
                const float* rbA = (st0 ? u_rb : s_rb) + l * 16;
                const float* rsA = (st0 ? u_rs : s_rs) + l * 96;
                const float* rbBp2 = (nb == 2 ? u_rb : rbA - l * 16) + l * 16;
                const float* rsBp2 = (nb == 2 ? u_rs : rsA - l * 96) + l * 96;
                k_bias<<<dim3(1296, nb), 256, 0, stream>>>(rbA, rsA, rbBp2, rsBp2, BIASp);
            }
            k_attn2<<<dim3(18, NHEADS, nb * 8), 256, 0, stream>>>(QKVb, BIASp, OBp);
            // proj
            k_expand7<<<Mr * 64 / 256, 256, 0, stream>>>(OBp, AEXP, Mr);
            mgemm<128, 64, 0, 0><<<4 * (Mr / 128), 256, 0, stream>>>(
                AEXP, Wp + (size_t)st0 * nWp, Wp + nWp, (void*)SEbp, 256, 1792, 1792, 4, TT);
            // refine w1 (+gelu, bf16 out)
            k_expand7<<<Mr * 64 / 256, 256, 0, stream>>>(SEbp, AEXP, Mr);
            mgemm<128, 128, 1, 2><<<8 * (Mr / 128), 256, 0, stream>>>(
                AEXP, Ww1, Ww1, (void*)H1bp, 1024, 1792, 1792, 8, TT);
            // refine w2: base pass + per-stream spline halves (accumulate)
            mgemm<64, 64, 0, 0><<<4 * (Mr / 64), 256, 0, stream>>>(
                H1bp, Ww2b, Ww2b, (void*)H2p, 256, 1024, 1024, 4, TT);
            for (int ss = 0; ss < nb; ss++) {
                for (int hf = 0; hf < 2; hf++) {
                    k_ex_half<<<TT * 128 / 256, 256, 0, stream>>>(
                        H1bp + (size_t)ss * TT * 1024, AEXP, hf * 512);
                    mgemm<64, 64, 0, 1><<<4 * (TT / 64), 256, 0, stream>>>(
                        AEXP, Ww2s + hf * 3072, Ww2s + hf * 3072,
                        (void*)(H2p + (size_t)ss * TT * 256), 256, 3072, 6144, 4, TT);
                }
            }
            // LN + residual -> X
            k_ln_add<<<Mr, 256, 0, stream>>>(H2p, SEbp, r_lng + l * 256, r_lnb + l * 256, Xs);
        }
    }

    // final head (fp32, tiny)
    k_meanpool<<<8, 256, 0, stream>>>(X, si, 0);
    k_meanpool<<<8, 256, 0, stream>>>(X + (size_t)TT * 256, si, 256);
    k_expand<<<(BB * 512 + 255) / 256, 256, 0, stream>>>(si, SB, BB * 512);
    k_small_kan<<<dim3(1024, BB), 64, 0, stream>>>(si, 512, SB, 3072, m_w1b, m_w1s, h1f, 1024, 1);
    k_expand<<<(BB * 1024 + 255) / 256, 256, 0, stream>>>(h1f, SB, BB * 1024);
    k_small_kan<<<dim3(64, BB), 64, 0, stream>>>(h1f, 1024, SB, 6144, m_w2b, m_w2s, h2f, 64, 1);
    k_expand<<<(BB * 64 + 255) / 256, 256, 0, stream>>>(h2f, SB, BB * 64);
    k_small_kan<<<dim3(1, BB), 64, 0, stream>>>(h2f, 64, SB, 384, m_w3b, m_w3s, wvv, 1, 2);
    k_fi<<<16, 256, 0, stream>>>(si, wvv, fiB);
    k_expand<<<(BB * 512 + 255) / 256, 256, 0, stream>>>(fiB, SB, BB * 512);
    k_small_kan<<<dim3(256, BB), 64, 0, stream>>>(fiB, 512, SB, 3072, f_wb, f_ws, ftmp, 256, 0);
    k_ln_gelu<<<8, 256, 0, stream>>>(ftmp, f_lng, f_lnb, (float*)d_out);
}